// Round 2
// baseline (110.779 us; speedup 1.0000x reference)
//
#include <hip/hip_runtime.h>

#define NPTS 16384
#define NB   8
#define NM   2048
#define NC   128
#define EPSF 1e-8f

#define TQ   16                     // threads per query
#define QPB  16                     // queries per 256-thread block
#define GX   160                    // blocks per batch: 2560 slots >> segN(~2100) -> no tail

// Sorted top-3 insert via min/med3 (3 VALU for the distance regs) + 5 cndmask for
// indices (strict '<' -> earliest j kept on ties; per-thread j strictly increases).
#define MERGE3(d, j) do {                                       \
    const bool _b0 = (d) < D0;                                  \
    const bool _b1 = (d) < D1;                                  \
    const bool _b2 = (d) < D2;                                  \
    const float _n0 = fminf((d), D0);                           \
    const float _n1 = __builtin_amdgcn_fmed3f(D0, D1, (d));     \
    const float _n2 = __builtin_amdgcn_fmed3f(D1, D2, (d));     \
    I2 = _b1 ? I1 : (_b2 ? (j) : I2);                           \
    I1 = _b0 ? I0 : (_b1 ? (j) : I1);                           \
    I0 = _b0 ? (j) : I0;                                        \
    D0 = _n0; D1 = _n1; D2 = _n2;                               \
} while (0)

// Cross-thread merge element: full lexicographic (d, idx) compare (once per query)
#define MERGE_DI(ed, ei) do {                                           \
    const bool _b2 = ((ed) < D2) || (((ed) == D2) && ((ei) < I2));      \
    const bool _b1 = ((ed) < D1) || (((ed) == D1) && ((ei) < I1));      \
    const bool _b0 = ((ed) < D0) || (((ed) == D0) && ((ei) < I0));      \
    D2 = _b1 ? D1 : (_b2 ? (ed) : D2);                                  \
    I2 = _b1 ? I1 : (_b2 ? (ei) : I2);                                  \
    D1 = _b0 ? D0 : (_b1 ? (ed) : D1);                                  \
    I1 = _b0 ? I0 : (_b1 ? (ei) : I1);                                  \
    D0 = _b0 ? (ed) : D0;                                               \
    I0 = _b0 ? (ei) : I0;                                               \
} while (0)

// ---- dispatch 1: feats (B,C,m) -> ws (B,m,C), LDS-tiled so both sides coalesce ----
__global__ __launch_bounds__(256) void transpose_feats(const float* __restrict__ feats,
                                                       float* __restrict__ ws) {
    __shared__ float tile[64][NC + 1];   // +1 pad: write phase lanes hit distinct banks
    const int b   = blockIdx.y;
    const int j0  = blockIdx.x * 64;     // m-chunk
    const int tid = threadIdx.x;
    const float* src = feats + (size_t)b * NC * NM;
    float*       dst = ws    + (size_t)b * NM * NC;
    {
        const int j  = tid & 63;         // lane -> contiguous in m: 256B coalesced reads
        const int c4 = tid >> 6;         // wave -> channel quarter
#pragma unroll
        for (int c0 = 0; c0 < NC; c0 += 4) {
            const int c = c0 + c4;
            tile[j][c] = src[(size_t)c * NM + j0 + j];
        }
    }
    __syncthreads();
    {
        const int c  = tid & 127;        // lane -> contiguous in c: coalesced writes
        const int j2 = tid >> 7;
#pragma unroll
        for (int jj = 0; jj < 64; jj += 2) {
            const int j = jj + j2;
            dst[(size_t)(j0 + j) * NC + c] = tile[j][c];
        }
    }
}

// ---- dispatch 2: selection identical to verified baseline; gather from transposed ws
//      (3 x 512B contiguous rows, float4) when useT, else original column gather. ----
__global__ __launch_bounds__(256, 4) void fused(const float* __restrict__ unknown,
                                                const float* __restrict__ known,
                                                const int*   __restrict__ binds,
                                                const float* __restrict__ feats,
                                                const float* __restrict__ ws,
                                                const int useT,
                                                float* __restrict__ out) {
    __shared__ float2 kx2[NM / 2];  // 8 KB: {x[2p], x[2p+1]}
    __shared__ float2 ky2[NM / 2];  // 8 KB
    __shared__ float2 kz2[NM / 2];  // 8 KB
    __shared__ int qlist[QPB];
    __shared__ int wsum[4];

    const int tid  = threadIdx.x;
    const int b    = blockIdx.y;
    const int x    = blockIdx.x;
    const int lane = tid & 63;
    const int wave = tid >> 6;

    // ---- scan binds: per-thread count of batch-b points, 256-thread exclusive prefix ----
    const int4* b4 = (const int4*)binds;   // thread t owns binds[t*64 .. t*64+63]
    int myCnt = 0;
#pragma unroll
    for (int r = 0; r < 16; ++r) {
        const int4 v = b4[tid * 16 + r];
        myCnt += (v.x == b) + (v.y == b) + (v.z == b) + (v.w == b);
    }
    int inc = myCnt;
#pragma unroll
    for (int off = 1; off <= 32; off <<= 1) {
        const int n = __shfl_up(inc, off);
        if (lane >= off) inc += n;
    }
    if (lane == 63) wsum[wave] = inc;
    __syncthreads();
    int wbase = 0;
    for (int w = 0; w < wave; ++w) wbase += wsum[w];
    const int exPre = wbase + inc - myCnt;
    const int segN  = wsum[0] + wsum[1] + wsum[2] + wsum[3];

    if (x * QPB >= segN) return;           // block-uniform early exit

    // ---- stage known points of batch b into pair-SoA LDS ----
    {
        const float* kb = known + (size_t)b * NM * 3;
        for (int p = tid; p < NM / 2; p += 256) {
            const float* s = kb + p * 6;
            float2 vx, vy, vz;
            vx.x = s[0]; vy.x = s[1]; vz.x = s[2];
            vx.y = s[3]; vy.y = s[4]; vz.y = s[5];
            kx2[p] = vx; ky2[p] = vy; kz2[p] = vz;
        }
    }

    const int qi = tid >> 4;   // query within block, 0..15
    const int t  = tid & 15;   // thread within query group

    for (int w0 = x * QPB; w0 < segN; w0 += GX * QPB) {
        __syncthreads();       // staging complete / previous window's qlist reads done
        if (exPre < w0 + QPB && exPre + myCnt > w0) {
            int rank = exPre;
#pragma unroll
            for (int r = 0; r < 16; ++r) {
                const int4 v = b4[tid * 16 + r];
                const int base = tid * 64 + r * 4;
                if (v.x == b) { if (rank >= w0 && rank < w0 + QPB) qlist[rank - w0] = base + 0; ++rank; }
                if (v.y == b) { if (rank >= w0 && rank < w0 + QPB) qlist[rank - w0] = base + 1; ++rank; }
                if (v.z == b) { if (rank >= w0 && rank < w0 + QPB) qlist[rank - w0] = base + 2; ++rank; }
                if (v.w == b) { if (rank >= w0 && rank < w0 + QPB) qlist[rank - w0] = base + 3; ++rank; }
            }
        }
        __syncthreads();

        const int valid = (segN - w0 < QPB) ? (segN - w0) : QPB;
        const int kq    = (qi < valid) ? qi : 0;   // duplicate query -> identical bytes, benign
        const int p     = qlist[kq];
        const float ux = unknown[p * 3 + 0];
        const float uy = unknown[p * 3 + 1];
        const float uz = unknown[p * 3 + 2];

        float D0 = __builtin_inff(), D1 = __builtin_inff(), D2 = __builtin_inff();
        int   I0 = NM, I1 = NM, I2 = NM;

        // thread t handles point-pairs pr = i*16 + t  (points 2pr, 2pr+1), i = 0..63
#pragma unroll 8
        for (int i = 0; i < NM / (2 * TQ); ++i) {
            const int pr = (i << 4) | t;
            const float2 vx = kx2[pr];
            const float2 vy = ky2[pr];
            const float2 vz = kz2[pr];
            const int jLo = pr << 1;
            // strict rn, numpy association ((dx2+dy2)+dz2): selection bit-identical to ref
            const float dx0 = __fsub_rn(ux, vx.x);
            const float dy0 = __fsub_rn(uy, vy.x);
            const float dz0 = __fsub_rn(uz, vz.x);
            const float dx1 = __fsub_rn(ux, vx.y);
            const float dy1 = __fsub_rn(uy, vy.y);
            const float dz1 = __fsub_rn(uz, vz.y);
            const float dLo = __fadd_rn(__fadd_rn(__fmul_rn(dx0, dx0), __fmul_rn(dy0, dy0)),
                                        __fmul_rn(dz0, dz0));
            const float dHi = __fadd_rn(__fadd_rn(__fmul_rn(dx1, dx1), __fmul_rn(dy1, dy1)),
                                        __fmul_rn(dz1, dz1));
            MERGE3(dLo, jLo);
            MERGE3(dHi, jLo + 1);
        }

        // merge 16 partial top-3 lists (shfl_down tree; valid at group lane 0), broadcast
#pragma unroll
        for (int off = 8; off >= 1; off >>= 1) {
            const float e0d = __shfl_down(D0, off);
            const float e1d = __shfl_down(D1, off);
            const float e2d = __shfl_down(D2, off);
            const int   e0i = __shfl_down(I0, off);
            const int   e1i = __shfl_down(I1, off);
            const int   e2i = __shfl_down(I2, off);
            MERGE_DI(e0d, e0i);
            MERGE_DI(e1d, e1i);
            MERGE_DI(e2d, e2i);
        }
        const int src = lane & ~15;
        D0 = __shfl(D0, src); D1 = __shfl(D1, src); D2 = __shfl(D2, src);
        I0 = __shfl(I0, src); I1 = __shfl(I1, src); I2 = __shfl(I2, src);

        const float t0 = 1.0f / (sqrtf(D0) + EPSF);
        const float t1 = 1.0f / (sqrtf(D1) + EPSF);
        const float t2 = 1.0f / (sqrtf(D2) + EPSF);
        const float s  = t0 + t1 + t2;
        const float w0w = t0 / s, w1w = t1 / s, w2w = t2 / s;

        if (useT) {
            // transposed gather: 3 x 512B contiguous rows, float4-coalesced
            const float* fb2 = ws + (size_t)b * NM * NC;
            const float4* r0 = (const float4*)(fb2 + (size_t)I0 * NC);
            const float4* r1 = (const float4*)(fb2 + (size_t)I1 * NC);
            const float4* r2 = (const float4*)(fb2 + (size_t)I2 * NC);
            float4* op = (float4*)(out + (size_t)p * NC);
#pragma unroll
            for (int k = 0; k < 2; ++k) {
                const int c4 = t + (k << 4);       // float4 index 0..31 -> 128B/group/instr
                const float4 f0 = r0[c4];
                const float4 f1 = r1[c4];
                const float4 f2 = r2[c4];
                float4 o;
                o.x = w0w * f0.x + w1w * f1.x + w2w * f2.x;
                o.y = w0w * f0.y + w1w * f1.y + w2w * f2.y;
                o.z = w0w * f0.z + w1w * f1.z + w2w * f2.z;
                o.w = w0w * f0.w + w1w * f1.w + w2w * f2.w;
                op[c4] = o;
            }
        } else {
            // fallback (ws too small): original column gather from raw (B,C,m)
            const float* fb = feats + (size_t)b * NC * NM;
#pragma unroll
            for (int k = 0; k < 8; ++k) {
                const int c = t + (k << 4);
                const float* fc = fb + (size_t)c * NM;
                const float f0 = fc[I0];
                const float f1 = fc[I1];
                const float f2 = fc[I2];
                out[(size_t)p * NC + c] = w0w * f0 + w1w * f1 + w2w * f2;
            }
        }
    }
}

extern "C" void kernel_launch(void* const* d_in, const int* in_sizes, int n_in,
                              void* d_out, int out_size, void* d_ws, size_t ws_size,
                              hipStream_t stream) {
    const float* unknown = (const float*)d_in[0];   // (n, 3)
    const float* known   = (const float*)d_in[1];   // (B, m, 3)
    const int*   binds   = (const int*)d_in[2];     // (n,)
    const float* feats   = (const float*)d_in[3];   // (B, C, m)
    float*       out     = (float*)d_out;           // (n, C, 1)

    const size_t tsz = (size_t)NB * NC * NM * sizeof(float);   // 8 MB
    const int useT = (d_ws != nullptr && ws_size >= tsz) ? 1 : 0;
    float* ws = (float*)d_ws;

    if (useT) {
        transpose_feats<<<dim3(NM / 64, NB), 256, 0, stream>>>(feats, ws);
    }
    fused<<<dim3(GX, NB), 256, 0, stream>>>(unknown, known, binds, feats, ws, useT, out);
}

// Round 3
// 102.014 us; speedup vs baseline: 1.0859x; 1.0859x over previous
//
#include <hip/hip_runtime.h>

#define NPTS 16384
#define NB   8
#define NM   2048
#define NC   128
#define EPSF 1e-8f

#define TQ   16                     // threads per query
#define QPB  16                     // queries per 256-thread block
#define GX   160                    // blocks per batch: 2560 slots >> segN(~2100)
#define QSTRIDE 2560                // per-batch slot stride in qws

// Sorted top-3 insert via min/med3 (3 VALU for the distance regs) + 5 cndmask for
// indices (strict '<' -> earliest j kept on ties; per-thread j strictly increases).
#define MERGE3(d, j) do {                                       \
    const bool _b0 = (d) < D0;                                  \
    const bool _b1 = (d) < D1;                                  \
    const bool _b2 = (d) < D2;                                  \
    const float _n0 = fminf((d), D0);                           \
    const float _n1 = __builtin_amdgcn_fmed3f(D0, D1, (d));     \
    const float _n2 = __builtin_amdgcn_fmed3f(D1, D2, (d));     \
    I2 = _b1 ? I1 : (_b2 ? (j) : I2);                           \
    I1 = _b0 ? I0 : (_b1 ? (j) : I1);                           \
    I0 = _b0 ? (j) : I0;                                        \
    D0 = _n0; D1 = _n1; D2 = _n2;                               \
} while (0)

// Cross-thread merge element: full lexicographic (d, idx) compare (once per query)
#define MERGE_DI(ed, ei) do {                                           \
    const bool _b2 = ((ed) < D2) || (((ed) == D2) && ((ei) < I2));      \
    const bool _b1 = ((ed) < D1) || (((ed) == D1) && ((ei) < I1));      \
    const bool _b0 = ((ed) < D0) || (((ed) == D0) && ((ei) < I0));      \
    D2 = _b1 ? D1 : (_b2 ? (ed) : D2);                                  \
    I2 = _b1 ? I1 : (_b2 ? (ei) : I2);                                  \
    D1 = _b0 ? D0 : (_b1 ? (ed) : D1);                                  \
    I1 = _b0 ? I0 : (_b1 ? (ei) : I1);                                  \
    D0 = _b0 ? (ed) : D0;                                               \
    I0 = _b0 ? (ei) : I0;                                               \
} while (0)

// ---- dispatch 1 (prep): blockIdx.x < 32 -> feats (B,C,m) -> ws (B,m,C) transpose tile;
//      blockIdx.x == 32 -> binds scan for batch b: compacted query list + segN into qws. ----
__global__ __launch_bounds__(256) void prep(const float* __restrict__ feats,
                                            const int*   __restrict__ binds,
                                            float* __restrict__ ws) {
    __shared__ float tile[64][NC + 1];
    __shared__ int wsum[4];
    const int b   = blockIdx.y;
    const int tid = threadIdx.x;

    if (blockIdx.x < NM / 64) {
        // ---- transpose tile (verified in R2) ----
        const int j0  = blockIdx.x * 64;
        const float* src = feats + (size_t)b * NC * NM;
        float*       dst = ws    + (size_t)b * NM * NC;
        {
            const int j  = tid & 63;     // lane -> contiguous in m: coalesced reads
            const int c4 = tid >> 6;
#pragma unroll
            for (int c0 = 0; c0 < NC; c0 += 4) {
                const int c = c0 + c4;
                tile[j][c] = src[(size_t)c * NM + j0 + j];
            }
        }
        __syncthreads();
        {
            const int c  = tid & 127;    // lane -> contiguous in c: coalesced writes
            const int j2 = tid >> 7;
#pragma unroll
            for (int jj = 0; jj < 64; jj += 2) {
                const int j = jj + j2;
                dst[(size_t)(j0 + j) * NC + c] = tile[j][c];
            }
        }
    } else {
        // ---- binds scan: identical arithmetic/order to the verified in-kernel scan ----
        int* qws = (int*)(ws + (size_t)NB * NM * NC);
        const int lane = tid & 63;
        const int wave = tid >> 6;
        const int4* b4 = (const int4*)binds;
        int myCnt = 0;
#pragma unroll
        for (int r = 0; r < 16; ++r) {
            const int4 v = b4[tid * 16 + r];
            myCnt += (v.x == b) + (v.y == b) + (v.z == b) + (v.w == b);
        }
        int inc = myCnt;
#pragma unroll
        for (int off = 1; off <= 32; off <<= 1) {
            const int n = __shfl_up(inc, off);
            if (lane >= off) inc += n;
        }
        if (lane == 63) wsum[wave] = inc;
        __syncthreads();
        int wbase = 0;
        for (int w = 0; w < wave; ++w) wbase += wsum[w];
        int rank = wbase + inc - myCnt;          // exclusive prefix = global rank
        int* qb = qws + b * QSTRIDE;
#pragma unroll
        for (int r = 0; r < 16; ++r) {
            const int4 v = b4[tid * 16 + r];
            const int base = tid * 64 + r * 4;
            if (v.x == b) qb[rank++] = base + 0;
            if (v.y == b) qb[rank++] = base + 1;
            if (v.z == b) qb[rank++] = base + 2;
            if (v.w == b) qb[rank++] = base + 3;
        }
        if (tid == 255) qws[NB * QSTRIDE + b] = wbase + inc;   // segN_b
    }
}

// ---- dispatch 2 (fast path): no binds scan; float4 LDS (half the ds_read issue);
//      transposed contiguous gather. Selection math bit-identical to verified kernel. ----
__global__ __launch_bounds__(256, 4) void fused_fast(const float* __restrict__ unknown,
                                                     const float* __restrict__ known,
                                                     const float* __restrict__ ws,
                                                     float* __restrict__ out) {
    __shared__ float4 kx4[NM / 4];  // 8 KB: x of points {4q..4q+3}
    __shared__ float4 ky4[NM / 4];  // 8 KB
    __shared__ float4 kz4[NM / 4];  // 8 KB

    const int tid = threadIdx.x;
    const int b   = blockIdx.y;
    const int x   = blockIdx.x;

    const int* qws = (const int*)(ws + (size_t)NB * NM * NC);
    const int segN = qws[NB * QSTRIDE + b];
    if (x * QPB >= segN) return;           // block-uniform early exit (one int read)

    // ---- stage known points of batch b into quad-SoA LDS ----
    {
        const float* kb = known + (size_t)b * NM * 3;
        for (int q = tid; q < NM / 4; q += 256) {
            const float* s = kb + q * 12;
            kx4[q] = make_float4(s[0], s[3], s[6], s[9]);
            ky4[q] = make_float4(s[1], s[4], s[7], s[10]);
            kz4[q] = make_float4(s[2], s[5], s[8], s[11]);
        }
    }
    __syncthreads();

    const int qi = tid >> 4;   // query within block, 0..15
    const int t  = tid & 15;   // thread within query group
    const int* qb = qws + b * QSTRIDE;

    for (int w0 = x * QPB; w0 < segN; w0 += GX * QPB) {
        const int valid = (segN - w0 < QPB) ? (segN - w0) : QPB;
        const int kq    = (qi < valid) ? qi : 0;   // duplicate query -> benign
        const int p     = qb[w0 + kq];
        const float ux = unknown[p * 3 + 0];
        const float uy = unknown[p * 3 + 1];
        const float uz = unknown[p * 3 + 2];

        float D0 = __builtin_inff(), D1 = __builtin_inff(), D2 = __builtin_inff();
        int   I0 = NM, I1 = NM, I2 = NM;

        // thread t handles quads q = i*16 + t (points 4q..4q+3), i = 0..31
#pragma unroll 4
        for (int i = 0; i < NM / (4 * TQ); ++i) {
            const int q = (i << 4) | t;
            const float4 vx = kx4[q];
            const float4 vy = ky4[q];
            const float4 vz = kz4[q];
            const int j = q << 2;
            // strict rn, numpy association ((dx2+dy2)+dz2): selection bit-identical to ref
            {
                const float dx = __fsub_rn(ux, vx.x), dy = __fsub_rn(uy, vy.x), dz = __fsub_rn(uz, vz.x);
                const float d  = __fadd_rn(__fadd_rn(__fmul_rn(dx, dx), __fmul_rn(dy, dy)), __fmul_rn(dz, dz));
                MERGE3(d, j);
            }
            {
                const float dx = __fsub_rn(ux, vx.y), dy = __fsub_rn(uy, vy.y), dz = __fsub_rn(uz, vz.y);
                const float d  = __fadd_rn(__fadd_rn(__fmul_rn(dx, dx), __fmul_rn(dy, dy)), __fmul_rn(dz, dz));
                MERGE3(d, j + 1);
            }
            {
                const float dx = __fsub_rn(ux, vx.z), dy = __fsub_rn(uy, vy.z), dz = __fsub_rn(uz, vz.z);
                const float d  = __fadd_rn(__fadd_rn(__fmul_rn(dx, dx), __fmul_rn(dy, dy)), __fmul_rn(dz, dz));
                MERGE3(d, j + 2);
            }
            {
                const float dx = __fsub_rn(ux, vx.w), dy = __fsub_rn(uy, vy.w), dz = __fsub_rn(uz, vz.w);
                const float d  = __fadd_rn(__fadd_rn(__fmul_rn(dx, dx), __fmul_rn(dy, dy)), __fmul_rn(dz, dz));
                MERGE3(d, j + 3);
            }
        }

        // merge 16 partial top-3 lists (shfl_down tree; valid at group lane 0), broadcast
        const int lane = tid & 63;
#pragma unroll
        for (int off = 8; off >= 1; off >>= 1) {
            const float e0d = __shfl_down(D0, off);
            const float e1d = __shfl_down(D1, off);
            const float e2d = __shfl_down(D2, off);
            const int   e0i = __shfl_down(I0, off);
            const int   e1i = __shfl_down(I1, off);
            const int   e2i = __shfl_down(I2, off);
            MERGE_DI(e0d, e0i);
            MERGE_DI(e1d, e1i);
            MERGE_DI(e2d, e2i);
        }
        const int src = lane & ~15;
        D0 = __shfl(D0, src); D1 = __shfl(D1, src); D2 = __shfl(D2, src);
        I0 = __shfl(I0, src); I1 = __shfl(I1, src); I2 = __shfl(I2, src);

        const float t0 = 1.0f / (sqrtf(D0) + EPSF);
        const float t1 = 1.0f / (sqrtf(D1) + EPSF);
        const float t2 = 1.0f / (sqrtf(D2) + EPSF);
        const float s  = t0 + t1 + t2;
        const float w0w = t0 / s, w1w = t1 / s, w2w = t2 / s;

        // transposed gather: 3 x 512B contiguous rows, float4-coalesced (verified R2)
        const float* fb2 = ws + (size_t)b * NM * NC;
        const float4* r0 = (const float4*)(fb2 + (size_t)I0 * NC);
        const float4* r1 = (const float4*)(fb2 + (size_t)I1 * NC);
        const float4* r2 = (const float4*)(fb2 + (size_t)I2 * NC);
        float4* op = (float4*)(out + (size_t)p * NC);
#pragma unroll
        for (int k = 0; k < 2; ++k) {
            const int c4 = t + (k << 4);
            const float4 f0 = r0[c4];
            const float4 f1 = r1[c4];
            const float4 f2 = r2[c4];
            float4 o;
            o.x = w0w * f0.x + w1w * f1.x + w2w * f2.x;
            o.y = w0w * f0.y + w1w * f1.y + w2w * f2.y;
            o.z = w0w * f0.z + w1w * f1.z + w2w * f2.z;
            o.w = w0w * f0.w + w1w * f1.w + w2w * f2.w;
            op[c4] = o;
        }
    }
}

// ---- fallback: exact verified baseline (single dispatch, no workspace) ----
__global__ __launch_bounds__(256, 4) void fused(const float* __restrict__ unknown,
                                                const float* __restrict__ known,
                                                const int*   __restrict__ binds,
                                                const float* __restrict__ feats,
                                                float* __restrict__ out) {
    __shared__ float2 kx2[NM / 2];
    __shared__ float2 ky2[NM / 2];
    __shared__ float2 kz2[NM / 2];
    __shared__ int qlist[QPB];
    __shared__ int wsum[4];

    const int tid  = threadIdx.x;
    const int b    = blockIdx.y;
    const int x    = blockIdx.x;
    const int lane = tid & 63;
    const int wave = tid >> 6;

    const int4* b4 = (const int4*)binds;
    int myCnt = 0;
#pragma unroll
    for (int r = 0; r < 16; ++r) {
        const int4 v = b4[tid * 16 + r];
        myCnt += (v.x == b) + (v.y == b) + (v.z == b) + (v.w == b);
    }
    int inc = myCnt;
#pragma unroll
    for (int off = 1; off <= 32; off <<= 1) {
        const int n = __shfl_up(inc, off);
        if (lane >= off) inc += n;
    }
    if (lane == 63) wsum[wave] = inc;
    __syncthreads();
    int wbase = 0;
    for (int w = 0; w < wave; ++w) wbase += wsum[w];
    const int exPre = wbase + inc - myCnt;
    const int segN  = wsum[0] + wsum[1] + wsum[2] + wsum[3];

    if (x * QPB >= segN) return;

    {
        const float* kb = known + (size_t)b * NM * 3;
        for (int p = tid; p < NM / 2; p += 256) {
            const float* s = kb + p * 6;
            float2 vx, vy, vz;
            vx.x = s[0]; vy.x = s[1]; vz.x = s[2];
            vx.y = s[3]; vy.y = s[4]; vz.y = s[5];
            kx2[p] = vx; ky2[p] = vy; kz2[p] = vz;
        }
    }

    const int qi = tid >> 4;
    const int t  = tid & 15;

    for (int w0 = x * QPB; w0 < segN; w0 += GX * QPB) {
        __syncthreads();
        if (exPre < w0 + QPB && exPre + myCnt > w0) {
            int rank = exPre;
#pragma unroll
            for (int r = 0; r < 16; ++r) {
                const int4 v = b4[tid * 16 + r];
                const int base = tid * 64 + r * 4;
                if (v.x == b) { if (rank >= w0 && rank < w0 + QPB) qlist[rank - w0] = base + 0; ++rank; }
                if (v.y == b) { if (rank >= w0 && rank < w0 + QPB) qlist[rank - w0] = base + 1; ++rank; }
                if (v.z == b) { if (rank >= w0 && rank < w0 + QPB) qlist[rank - w0] = base + 2; ++rank; }
                if (v.w == b) { if (rank >= w0 && rank < w0 + QPB) qlist[rank - w0] = base + 3; ++rank; }
            }
        }
        __syncthreads();

        const int valid = (segN - w0 < QPB) ? (segN - w0) : QPB;
        const int kq    = (qi < valid) ? qi : 0;
        const int p     = qlist[kq];
        const float ux = unknown[p * 3 + 0];
        const float uy = unknown[p * 3 + 1];
        const float uz = unknown[p * 3 + 2];

        float D0 = __builtin_inff(), D1 = __builtin_inff(), D2 = __builtin_inff();
        int   I0 = NM, I1 = NM, I2 = NM;

#pragma unroll 8
        for (int i = 0; i < NM / (2 * TQ); ++i) {
            const int pr = (i << 4) | t;
            const float2 vx = kx2[pr];
            const float2 vy = ky2[pr];
            const float2 vz = kz2[pr];
            const int jLo = pr << 1;
            const float dx0 = __fsub_rn(ux, vx.x);
            const float dy0 = __fsub_rn(uy, vy.x);
            const float dz0 = __fsub_rn(uz, vz.x);
            const float dx1 = __fsub_rn(ux, vx.y);
            const float dy1 = __fsub_rn(uy, vy.y);
            const float dz1 = __fsub_rn(uz, vz.y);
            const float dLo = __fadd_rn(__fadd_rn(__fmul_rn(dx0, dx0), __fmul_rn(dy0, dy0)),
                                        __fmul_rn(dz0, dz0));
            const float dHi = __fadd_rn(__fadd_rn(__fmul_rn(dx1, dx1), __fmul_rn(dy1, dy1)),
                                        __fmul_rn(dz1, dz1));
            MERGE3(dLo, jLo);
            MERGE3(dHi, jLo + 1);
        }

#pragma unroll
        for (int off = 8; off >= 1; off >>= 1) {
            const float e0d = __shfl_down(D0, off);
            const float e1d = __shfl_down(D1, off);
            const float e2d = __shfl_down(D2, off);
            const int   e0i = __shfl_down(I0, off);
            const int   e1i = __shfl_down(I1, off);
            const int   e2i = __shfl_down(I2, off);
            MERGE_DI(e0d, e0i);
            MERGE_DI(e1d, e1i);
            MERGE_DI(e2d, e2i);
        }
        const int src = lane & ~15;
        D0 = __shfl(D0, src); D1 = __shfl(D1, src); D2 = __shfl(D2, src);
        I0 = __shfl(I0, src); I1 = __shfl(I1, src); I2 = __shfl(I2, src);

        const float t0 = 1.0f / (sqrtf(D0) + EPSF);
        const float t1 = 1.0f / (sqrtf(D1) + EPSF);
        const float t2 = 1.0f / (sqrtf(D2) + EPSF);
        const float s  = t0 + t1 + t2;
        const float w0w = t0 / s, w1w = t1 / s, w2w = t2 / s;

        const float* fb = feats + (size_t)b * NC * NM;
#pragma unroll
        for (int k = 0; k < 8; ++k) {
            const int c = t + (k << 4);
            const float* fc = fb + (size_t)c * NM;
            const float f0 = fc[I0];
            const float f1 = fc[I1];
            const float f2 = fc[I2];
            out[(size_t)p * NC + c] = w0w * f0 + w1w * f1 + w2w * f2;
        }
    }
}

extern "C" void kernel_launch(void* const* d_in, const int* in_sizes, int n_in,
                              void* d_out, int out_size, void* d_ws, size_t ws_size,
                              hipStream_t stream) {
    const float* unknown = (const float*)d_in[0];   // (n, 3)
    const float* known   = (const float*)d_in[1];   // (B, m, 3)
    const int*   binds   = (const int*)d_in[2];     // (n,)
    const float* feats   = (const float*)d_in[3];   // (B, C, m)
    float*       out     = (float*)d_out;           // (n, C, 1)

    const size_t fsz = (size_t)NB * NC * NM * sizeof(float);            // 8 MB transpose
    const size_t qsz = (size_t)(NB * QSTRIDE + NB) * sizeof(int);       // query lists + segN
    float* ws = (float*)d_ws;

    if (ws != nullptr && ws_size >= fsz + qsz) {
        prep<<<dim3(NM / 64 + 1, NB), 256, 0, stream>>>(feats, binds, ws);
        fused_fast<<<dim3(GX, NB), 256, 0, stream>>>(unknown, known, ws, out);
    } else {
        fused<<<dim3(GX, NB), 256, 0, stream>>>(unknown, known, binds, feats, out);
    }
}